// Round 1
// baseline (95.627 us; speedup 1.0000x reference)
//
#include <hip/hip_runtime.h>

#define ALPHA 5
#define VOCAB 3875      // 5^3 + 5^4 + 5^5
#define SEQ   512
#define G3    (SEQ - 2) // 510 trigram windows
#define G4    (SEQ - 3) // 509
#define G5    (SEQ - 4) // 508
#define NG    (G3 + G4 + G5) // 1527
#define OFF3  0
#define OFF4  125
#define OFF5  750       // 125 + 625

__global__ __launch_bounds__(256) void ngram_rowhist_kernel(
        const int* __restrict__ tokens,
        const float* __restrict__ values,
        float* __restrict__ out) {
    __shared__ int tok[SEQ];
    __shared__ unsigned int row[VOCAB];

    const int b   = blockIdx.x;
    const int tid = threadIdx.x;

    // --- stage tokens (coalesced) and zero the LDS row histogram ---
    const int* trow = tokens + (size_t)b * SEQ;
    #pragma unroll
    for (int i = tid; i < SEQ; i += 256) tok[i] = trow[i];
    #pragma unroll
    for (int i = tid; i < VOCAB; i += 256) row[i] = 0u;
    __syncthreads();

    // --- compute n-gram indices + scatter-max into LDS ---
    // Position i yields: idx3(i) = t0*25 + t1*5 + t2
    //                    idx4(i) = idx3(i)*5 + t3
    //                    idx5(i) = idx4(i)*5 + t4
    // values layout: [0,510) n=3 | [510,1019) n=4 | [1019,1527) n=5
    const float* vrow = values + (size_t)b * NG;
    for (int i = tid; i < G3; i += 256) {
        const int t0 = tok[i], t1 = tok[i + 1], t2 = tok[i + 2];
        const int i3 = t0 * 25 + t1 * 5 + t2;
        {
            const float v = fmaxf(vrow[i], 0.0f);
            atomicMax(&row[OFF3 + i3], __float_as_uint(v));
        }
        if (i < G4) {
            const int i4 = i3 * 5 + tok[i + 3];
            const float v = fmaxf(vrow[G3 + i], 0.0f);
            atomicMax(&row[OFF4 + i4], __float_as_uint(v));
            if (i < G5) {
                const int i5 = i4 * 5 + tok[i + 4];
                const float v5 = fmaxf(vrow[G3 + G4 + i], 0.0f);
                atomicMax(&row[OFF5 + i5], __float_as_uint(v5));
            }
        }
    }
    __syncthreads();

    // --- stream the finished row to HBM (coalesced dword stores) ---
    float* orow = out + (size_t)b * VOCAB;
    #pragma unroll
    for (int i = tid; i < VOCAB; i += 256) orow[i] = __uint_as_float(row[i]);
}

extern "C" void kernel_launch(void* const* d_in, const int* in_sizes, int n_in,
                              void* d_out, int out_size, void* d_ws, size_t ws_size,
                              hipStream_t stream) {
    const int*   tokens = (const int*)d_in[0];
    const float* values = (const float*)d_in[1];
    float*       out    = (float*)d_out;

    const int B = in_sizes[0] / SEQ; // 4096
    ngram_rowhist_kernel<<<B, 256, 0, stream>>>(tokens, values, out);
}

// Round 2
// 95.459 us; speedup vs baseline: 1.0018x; 1.0018x over previous
//
#include <hip/hip_runtime.h>

#define ALPHA 5
#define VOCAB 3875      // 5^3 + 5^4 + 5^5
#define SEQ   512
#define G3    (SEQ - 2) // 510 trigram windows
#define G4    (SEQ - 3) // 509
#define G5    (SEQ - 4) // 508
#define NG    (G3 + G4 + G5) // 1527
#define OFF4  125
#define OFF5  750       // 125 + 625
#define NT    512       // threads per block (8 waves)

__global__ __launch_bounds__(NT) void ngram_rowhist_kernel(
        const int* __restrict__ tokens,
        const float* __restrict__ values,
        float* __restrict__ out) {
    __shared__ int tok[SEQ];
    __shared__ __align__(16) unsigned int row[VOCAB];

    const int b   = blockIdx.x;
    const int tid = threadIdx.x;

    // --- phase 0: issue ALL global reads up front (latency hides under zeroing) ---
    const int myTok = tokens[(size_t)b * SEQ + tid];     // 1 dword/lane, coalesced

    const float* vrow = values + (size_t)b * NG;
    float v3 = 0.f, v4 = 0.f, v5 = 0.f;
    if (tid < G3) v3 = vrow[tid];
    if (tid < G4) v4 = vrow[G3 + tid];
    if (tid < G5) v5 = vrow[G3 + G4 + tid];

    // --- phase 1: zero the LDS histogram (vectorized) while loads are in flight ---
    uint4* row4 = (uint4*)row;                            // 3875 = 968*4 + 3
    #pragma unroll
    for (int i = tid; i < 968; i += NT) row4[i] = make_uint4(0u, 0u, 0u, 0u);
    if (tid < 3) row[3872 + tid] = 0u;

    tok[tid] = myTok;
    __syncthreads();

    // --- phase 2: one window per thread, chained base-5 indices, LDS atomicMax ---
    // idx3 = t0*25 + t1*5 + t2 ; idx4 = idx3*5 + t3 ; idx5 = idx4*5 + t4
    if (tid < G3) {
        const int t1 = tok[tid + 1], t2 = tok[tid + 2];
        const int i3 = myTok * 25 + t1 * 5 + t2;
        atomicMax(&row[i3], __float_as_uint(fmaxf(v3, 0.0f)));
        if (tid < G4) {
            const int i4 = i3 * 5 + tok[tid + 3];
            atomicMax(&row[OFF4 + i4], __float_as_uint(fmaxf(v4, 0.0f)));
            if (tid < G5) {
                const int i5 = i4 * 5 + tok[tid + 4];
                atomicMax(&row[OFF5 + i5], __float_as_uint(fmaxf(v5, 0.0f)));
            }
        }
    }
    __syncthreads();

    // --- phase 3: stream the row to HBM (scalar dwords = already fully coalesced;
    // out rows are only 4B-aligned (3875*4 B stride) so no float4 here) ---
    float* orow = out + (size_t)b * VOCAB;
    #pragma unroll
    for (int i = tid; i < VOCAB; i += NT) orow[i] = __uint_as_float(row[i]);
}

extern "C" void kernel_launch(void* const* d_in, const int* in_sizes, int n_in,
                              void* d_out, int out_size, void* d_ws, size_t ws_size,
                              hipStream_t stream) {
    const int*   tokens = (const int*)d_in[0];
    const float* values = (const float*)d_in[1];
    float*       out    = (float*)d_out;

    const int B = in_sizes[0] / SEQ; // 4096
    ngram_rowhist_kernel<<<B, NT, 0, stream>>>(tokens, values, out);
}